// Round 8
// baseline (176.675 us; speedup 1.0000x reference)
//
#include <hip/hip_runtime.h>
#include <hip/hip_bf16.h>

// Problem constants (B,C,T,H,W = 4,128,16,32,32)
#define NB 4
#define NC 128
#define NN 16384   // T*H*W
#define NM 2048    // pooled positions

typedef __attribute__((ext_vector_type(8))) short bf16x8;
typedef __attribute__((ext_vector_type(4))) float f32x4;
typedef __attribute__((ext_vector_type(4))) unsigned short u16x4;
typedef __attribute__((ext_vector_type(2))) unsigned int u32x2;
typedef unsigned short us;

#define MFMA16(a,b,c) __builtin_amdgcn_mfma_f32_16x16x32_bf16((a),(b),(c),0,0,0)

__device__ __forceinline__ us f2bf(float f){
  unsigned int u = __float_as_uint(f);
  u += 0x7fffu + ((u >> 16) & 1u);          // RNE
  return (us)(u >> 16);
}
__device__ __forceinline__ float bf2f(us h){
  return __uint_as_float(((unsigned int)h) << 16);
}
// pack two positive floats as bf16 pair (truncation; lo in low half) — round-2-proven
__device__ __forceinline__ unsigned int packbf2(float lo, float hi){
  return (__float_as_uint(hi) & 0xffff0000u) | (__float_as_uint(lo) >> 16);
}

// ---------------- K0: weight prep (fp32 -> bf16, concat) — round-2-proven (no L2E) ----------------
__global__ void k0_prep(const float* __restrict__ wf, const float* __restrict__ wg,
                        const float* __restrict__ wh, const float* __restrict__ bfp,
                        const float* __restrict__ bgp, const float* __restrict__ bhp,
                        const float* __restrict__ wo,
                        us* __restrict__ Wcat, us* __restrict__ wob,
                        float* __restrict__ bcat){
  int i = blockIdx.x * 256 + threadIdx.x;
  if (i < 16384){
    int o = i >> 7, c = i & 127;
    float v = (o < 32) ? wf[o*128 + c] : (o < 64) ? wg[(o-32)*128 + c] : wh[(o-64)*128 + c];
    Wcat[i] = f2bf(v);
  } else if (i < 24576){
    wob[i - 16384] = f2bf(wo[i - 16384]);
  } else if (i < 24704){
    int k = i - 24576;
    bcat[k] = (k < 32) ? bfp[k] : (k < 64) ? bgp[k-32] : bhp[k-64];
  }
}

// ---------------- K2: fused transpose + 3-conv + relu + w/h-pool (under test) ----------------
__global__ __launch_bounds__(256, 4) void k2_conv(
    const float* __restrict__ x, const us* __restrict__ Wcat,
    const float* __restrict__ bcat,
    us* __restrict__ thetaT, us* __restrict__ Ywh){
  __shared__ __align__(16) us xtile[64*136];     // [n][c] pitch 136
  __shared__ __align__(16) us theta_sh[64*40];   // [n][c0..31] pitch 40
  __shared__ us Ytmp[96*33];                     // w-pooled rows 32..127
  int blk = blockIdx.x;                  // NB * NN/64 = 1024
  int b = blk >> 8, nblk = blk & 255;
  int n0 = nblk * 64;
  int tid = threadIdx.x;

  // stage x[b][c][n0..n0+63] fp32 -> xtile[n][c] bf16 via b128 writes
  {
    int nbase = (tid & 15) * 4;          // 4 n
    int c0 = (tid >> 4) * 8;             // 8 c
    float va[8][4];
    #pragma unroll
    for (int j = 0; j < 8; ++j){
      float4 v = *(const float4*)(x + ((size_t)(b*128 + c0 + j)) * NN + n0 + nbase);
      va[j][0]=v.x; va[j][1]=v.y; va[j][2]=v.z; va[j][3]=v.w;
    }
    #pragma unroll
    for (int nn = 0; nn < 4; ++nn){
      bf16x8 r;
      #pragma unroll
      for (int j = 0; j < 8; ++j) r[j] = (short)f2bf(va[j][nn]);
      *(bf16x8*)&xtile[(nbase+nn)*136 + c0] = r;
    }
  }
  __syncthreads();

  int lane = tid & 63, w = tid >> 6;
  int ln = lane & 15, gq = lane >> 4;
  bf16x8 xf[4];
  #pragma unroll
  for (int kf = 0; kf < 4; ++kf)
    xf[kf] = *(const bf16x8*)&xtile[(w*16+ln)*136 + kf*32 + gq*8];

  #pragma unroll
  for (int ot = 0; ot < 8; ++ot){
    f32x4 acc = {0.f,0.f,0.f,0.f};
    #pragma unroll
    for (int kf = 0; kf < 4; ++kf){
      bf16x8 wfr = *(const bf16x8*)(Wcat + (ot*16 + ln)*128 + kf*32 + gq*8);
      acc = MFMA16(wfr, xf[kf], acc);
    }
    float y[4];
    #pragma unroll
    for (int i = 0; i < 4; ++i){
      int o = ot*16 + gq*4 + i;
      float v = acc[i] + bcat[o];
      y[i] = v > 0.f ? v : 0.f;
    }
    if (ot < 2){
      u16x4 pk;
      #pragma unroll
      for (int i = 0; i < 4; ++i) pk[i] = f2bf(y[i]);
      *(u16x4*)&theta_sh[(w*16+ln)*40 + ot*16 + gq*4] = pk;
    } else {
      #pragma unroll
      for (int i = 0; i < 4; ++i){
        float ym = fmaxf(y[i], __shfl_xor(y[i], 1));
        if ((ln & 1) == 0){
          int r = ot*16 + gq*4 + i - 32;
          Ytmp[r*33 + ((w*16 + ln) >> 1)] = f2bf(ym);
        }
      }
    }
  }
  __syncthreads();

  // theta flush: coalesced 4KB per block
  {
    int row = tid >> 2, coff = (tid & 3) * 8;
    bf16x8 tv = *(const bf16x8*)&theta_sh[row*40 + coff];
    *(bf16x8*)(thetaT + ((size_t)b*NN + n0 + row)*32 + coff) = tv;
  }
  // h-pool: Ytmp[r][j] vs Ytmp[r][j+16] -> Ywh[b][r][t][h2*16 + j]
  int tt = n0 >> 10;          // t index
  int h2 = nblk & 15;         // h-pair index
  #pragma unroll
  for (int q = 0; q < 6; ++q){
    int idx = q*256 + tid;    // 96 r x 16 j
    int r = idx >> 4, j = idx & 15;
    us a = Ytmp[r*33 + j], bsh = Ytmp[r*33 + j + 16];
    us v = a > bsh ? a : bsh;   // bf16 >=0: unsigned compare == fmax
    Ywh[(((size_t)(b*96 + r))*16 + tt)*256 + h2*16 + j] = v;
  }
}

// ---------------- K3: t-pool -> phiT[b][m][32], g[b][c2][m] (under test) ----------------
__global__ void k3_pool(const us* __restrict__ Ywh,
                        us* __restrict__ phiT, us* __restrict__ g_){
  __shared__ us trans[64][36];
  int blk = blockIdx.x;
  int t = threadIdx.x;
  if (blk < 128){
    int b = blk >> 5, mseg = blk & 31;
    int m0 = mseg * 64;
    int u = m0 >> 8, p0 = m0 & 255;
    int c = t >> 3, mj = t & 7;
    const us* r0 = Ywh + (((size_t)(b*96 + c))*16 + 2*u)*256 + p0 + mj*8;
    const us* r1 = r0 + 256;
    #pragma unroll
    for (int k = 0; k < 8; ++k){
      us a = r0[k], bsh = r1[k];
      trans[mj*8 + k][c] = a > bsh ? a : bsh;
    }
    __syncthreads();
    int ml = t >> 2, cg = t & 3;
    u16x4 o0, o1;
    #pragma unroll
    for (int k = 0; k < 4; ++k){ o0[k] = trans[ml][cg*8 + k]; o1[k] = trans[ml][cg*8 + 4 + k]; }
    *(u16x4*)(phiT + ((size_t)b*NM + m0 + ml)*32 + cg*8)     = o0;
    *(u16x4*)(phiT + ((size_t)b*NM + m0 + ml)*32 + cg*8 + 4) = o1;
  } else {
    int blk2 = blk - 128;
    int b = blk2 >> 6, c2 = blk2 & 63;
    int u = t >> 5, p = (t & 31) * 8;
    const us* r0 = Ywh + (((size_t)(b*96 + 32 + c2))*16 + 2*u)*256 + p;
    const us* r1 = r0 + 256;
    u16x4 o0, o1;
    #pragma unroll
    for (int k = 0; k < 4; ++k){
      us a0 = r0[k],   b0 = r1[k];
      us a1 = r0[4+k], b1 = r1[4+k];
      o0[k] = a0 > b0 ? a0 : b0;
      o1[k] = a1 > b1 ? a1 : b1;
    }
    *(u16x4*)(g_ + ((size_t)(b*64 + c2))*NM + t*8)     = o0;
    *(u16x4*)(g_ + ((size_t)(b*64 + c2))*NM + t*8 + 4) = o1;
  }
}

// ---------------- K4: flash attention, key-split x2 — round-2-proven verbatim ----------------
__global__ __launch_bounds__(256, 4) void k4_attn(
    const us* __restrict__ thetaT, const us* __restrict__ phiT,
    const us* __restrict__ g_, us* __restrict__ pacc,
    float* __restrict__ lsumA){
  __shared__ __align__(16) us phi_lds[2][32][40];
  __shared__ __align__(16) us g_lds[2][64][40];
  __shared__ __align__(16) us P_lds[4][16][40];

  int bx = blockIdx.x;                               // 1024
  int b = bx >> 8, qb = (bx >> 1) & 127, kh = bx & 1;
  int tid = threadIdx.x;
  int lane = tid & 63, wv = tid >> 6;
  int ln = lane & 15, gq = lane >> 4;
  int nq = qb*128 + wv*32;
  int ch0 = kh * 32;                                 // this block's 32 key-chunks

  const us* thb = thetaT + (size_t)b*NN*32;
  const us* phb = phiT   + (size_t)b*NM*32;
  const us* gb  = g_     + (size_t)b*64*NM;

  bf16x8 thf0 = *(const bf16x8*)(thb + (size_t)(nq + ln)*32 + gq*8);
  bf16x8 thf1 = *(const bf16x8*)(thb + (size_t)(nq + 16 + ln)*32 + gq*8);

  f32x4 acc[2][4];
  #pragma unroll
  for (int q = 0; q < 2; ++q)
    #pragma unroll
    for (int c2t = 0; c2t < 4; ++c2t) acc[q][c2t] = (f32x4){0.f,0.f,0.f,0.f};
  float lsum0 = 0.f, lsum1 = 0.f;

  // staging: g by all 256 threads; phi by tid<128
  int gr = tid >> 2, gp = tid & 3;
  const us* sgp_g = gb + (size_t)gr*NM + ch0*32 + gp*8;
  us* slg0 = &g_lds[0][gr][gp*8];
  us* slg1 = &g_lds[1][gr][gp*8];
  bool hasphi = tid < 128;
  int pr = (tid >> 2) & 31, pp = tid & 3;
  const us* sgp_p = phb + ((size_t)(ch0*32 + pr))*32 + pp*8;
  us* slp0 = &phi_lds[0][pr][pp*8];
  us* slp1 = &phi_lds[1][pr][pp*8];

  { bf16x8 srg = *(const bf16x8*)(sgp_g); *(bf16x8*)slg0 = srg; }
  if (hasphi){ bf16x8 srp = *(const bf16x8*)(sgp_p); *(bf16x8*)slp0 = srp; }
  __syncthreads();

  bf16x8 srg_n = {}, srp_n = {};
  for (int lc = 0; lc < 32; ++lc){
    int cur = lc & 1;
    if (lc + 1 < 32){                             // issue-early (T14)
      srg_n = *(const bf16x8*)(sgp_g + (size_t)(lc+1)*32);
      if (hasphi) srp_n = *(const bf16x8*)(sgp_p + (size_t)(lc+1)*1024);
    }
    bf16x8 pf0 = *(const bf16x8*)(&phi_lds[cur][ln][gq*8]);
    bf16x8 pf1 = *(const bf16x8*)(&phi_lds[cur][16+ln][gq*8]);
    bf16x8 gf0 = *(const bf16x8*)(&g_lds[cur][ln][gq*8]);
    bf16x8 gf1 = *(const bf16x8*)(&g_lds[cur][16+ln][gq*8]);
    bf16x8 gf2 = *(const bf16x8*)(&g_lds[cur][32+ln][gq*8]);
    bf16x8 gf3 = *(const bf16x8*)(&g_lds[cur][48+ln][gq*8]);
    f32x4 z = {0.f,0.f,0.f,0.f};

    // ---- q tile 0 ----
    {
      f32x4 s0 = MFMA16(pf0, thf0, z);
      f32x4 s1 = MFMA16(pf1, thf0, z);
      float p0[4], p1[4];
      #pragma unroll
      for (int i = 0; i < 4; ++i){ p0[i] = __expf(s0[i]); p1[i] = __expf(s1[i]); }
      lsum0 += ((p0[0]+p0[1]) + (p0[2]+p0[3])) + ((p1[0]+p1[1]) + (p1[2]+p1[3]));
      u32x2 w0 = { packbf2(p0[0],p0[1]), packbf2(p0[2],p0[3]) };
      u32x2 w1 = { packbf2(p1[0],p1[1]), packbf2(p1[2],p1[3]) };
      *(u32x2*)(&P_lds[wv][ln][gq*4])      = w0;
      *(u32x2*)(&P_lds[wv][ln][16+gq*4])   = w1;
      bf16x8 paf = *(const bf16x8*)(&P_lds[wv][ln][gq*8]);
      acc[0][0] = MFMA16(paf, gf0, acc[0][0]);
      acc[0][1] = MFMA16(paf, gf1, acc[0][1]);
      acc[0][2] = MFMA16(paf, gf2, acc[0][2]);
      acc[0][3] = MFMA16(paf, gf3, acc[0][3]);
    }
    // ---- q tile 1 ----
    {
      f32x4 s0 = MFMA16(pf0, thf1, z);
      f32x4 s1 = MFMA16(pf1, thf1, z);
      float p0[4], p1[4];
      #pragma unroll
      for (int i = 0; i < 4; ++i){ p0[i] = __expf(s0[i]); p1[i] = __expf(s1[i]); }
      lsum1 += ((p0[0]+p0[1]) + (p0[2]+p0[3])) + ((p1[0]+p1[1]) + (p1[2]+p1[3]));
      u32x2 w0 = { packbf2(p0[0],p0[1]), packbf2(p0[2],p0[3]) };
      u32x2 w1 = { packbf2(p1[0],p1[1]), packbf2(p1[2],p1[3]) };
      *(u32x2*)(&P_lds[wv][ln][gq*4])      = w0;
      *(u32x2*)(&P_lds[wv][ln][16+gq*4])   = w1;
      bf16x8 paf = *(const bf16x8*)(&P_lds[wv][ln][gq*8]);
      acc[1][0] = MFMA16(paf, gf0, acc[1][0]);
      acc[1][1] = MFMA16(paf, gf1, acc[1][1]);
      acc[1][2] = MFMA16(paf, gf2, acc[1][2]);
      acc[1][3] = MFMA16(paf, gf3, acc[1][3]);
    }
    if (lc + 1 < 32){                             // write-late into other buffer
      *(bf16x8*)(((lc+1)&1) ? slg1 : slg0) = srg_n;
      if (hasphi) *(bf16x8*)(((lc+1)&1) ? slp1 : slp0) = srp_n;
    }
    __syncthreads();
  }

  lsum0 += __shfl_xor(lsum0, 16); lsum0 += __shfl_xor(lsum0, 32);
  lsum1 += __shfl_xor(lsum1, 16); lsum1 += __shfl_xor(lsum1, 32);

  // raw (unnormalized) partial acc -> pacc[kh][b][n][64] bf16; lsum -> lsumA[kh][b][n]
  us* pb = pacc + ((size_t)(kh*NB + b))*NN*64;
  #pragma unroll
  for (int i = 0; i < 4; ++i){
    int r0 = nq + gq*4 + i, r1 = nq + 16 + gq*4 + i;
    #pragma unroll
    for (int c2t = 0; c2t < 4; ++c2t){
      pb[(size_t)r0*64 + c2t*16 + ln] = f2bf(acc[0][c2t][i]);
      pb[(size_t)r1*64 + c2t*16 + ln] = f2bf(acc[1][c2t][i]);
    }
  }
  size_t lbase = ((size_t)(kh*NB + b))*NN;
  if (gq == 0)      lsumA[lbase + nq + ln]      = lsum0;
  else if (gq == 1) lsumA[lbase + nq + 16 + ln] = lsum1;
}

// ---------------- K5: combine halves + out = x + gamma*relu(wo @ ag + bo) (under test) ----------------
__device__ __forceinline__ bf16x8 combine8(bf16x8 a, bf16x8 b, float inv){
  bf16x8 r;
  #pragma unroll
  for (int k = 0; k < 8; ++k){
    float f = (bf2f((us)a[k]) + bf2f((us)b[k])) * inv;
    r[k] = (short)f2bf(f);
  }
  return r;
}

__global__ __launch_bounds__(256, 4) void k5_out(
    const float* __restrict__ x, const us* __restrict__ pacc,
    const float* __restrict__ lsumA,
    const us* __restrict__ wob, const float* __restrict__ bo,
    const float* __restrict__ gamma, float* __restrict__ out){
  __shared__ __align__(16) float vt[128*68];   // [o][n] pitch 68
  int blk = blockIdx.x;                 // 1024
  int b = blk >> 8, nblk = blk & 255;
  int n0 = nblk * 64;
  int tid = threadIdx.x;
  int lane = tid & 63, w = tid >> 6;
  int ln = lane & 15, gq = lane >> 4;
  int n = n0 + w*16 + ln;
  int nl = w*16 + ln;

  const us* p0 = pacc + ((size_t)b*NN + n)*64;
  const us* p1 = pacc + ((size_t)(NB + b)*NN + n)*64;
  float l = lsumA[(size_t)b*NN + n] + lsumA[(size_t)(NB + b)*NN + n];
  float inv = 1.0f / l;
  bf16x8 a0lo = *(const bf16x8*)(p0 + gq*8);
  bf16x8 a1lo = *(const bf16x8*)(p1 + gq*8);
  bf16x8 a0hi = *(const bf16x8*)(p0 + 32 + gq*8);
  bf16x8 a1hi = *(const bf16x8*)(p1 + 32 + gq*8);
  bf16x8 bfr0 = combine8(a0lo, a1lo, inv);
  bf16x8 bfr1 = combine8(a0hi, a1hi, inv);

  float gam = gamma[0];
  #pragma unroll
  for (int ot = 0; ot < 8; ++ot){
    f32x4 acc = {0.f,0.f,0.f,0.f};
    bf16x8 a0 = *(const bf16x8*)(wob + (ot*16 + ln)*64 + gq*8);
    bf16x8 a1 = *(const bf16x8*)(wob + (ot*16 + ln)*64 + 32 + gq*8);
    acc = MFMA16(a0, bfr0, acc);
    acc = MFMA16(a1, bfr1, acc);
    #pragma unroll
    for (int i = 0; i < 4; ++i){
      int o = ot*16 + gq*4 + i;
      float v = acc[i] + bo[o];
      v = v > 0.f ? v : 0.f;
      vt[o*68 + nl] = gam * v;
    }
  }
  __syncthreads();

  // coalesced epilogue: thread covers half an o-row (32 floats)
  int o = tid >> 1, half = tid & 1;
  const float* xr = x + ((size_t)b*128 + o)*NN + n0 + half*32;
  float* outr = out + ((size_t)b*128 + o)*NN + n0 + half*32;
  const float* vr = &vt[o*68 + half*32];
  #pragma unroll
  for (int k = 0; k < 8; ++k){
    float4 xv = *(const float4*)(xr + k*4);
    float4 dv = *(const float4*)(vr + k*4);
    float4 ov = { xv.x + dv.x, xv.y + dv.y, xv.z + dv.z, xv.w + dv.w };
    *(float4*)(outr + k*4) = ov;
  }
}

extern "C" void kernel_launch(void* const* d_in, const int* in_sizes, int n_in,
                              void* d_out, int out_size, void* d_ws, size_t ws_size,
                              hipStream_t stream){
  const float* x   = (const float*)d_in[0];
  const float* wf  = (const float*)d_in[1];
  const float* bfp = (const float*)d_in[2];
  const float* wg  = (const float*)d_in[3];
  const float* bgp = (const float*)d_in[4];
  const float* wh  = (const float*)d_in[5];
  const float* bhp = (const float*)d_in[6];
  const float* wo  = (const float*)d_in[7];
  const float* bo  = (const float*)d_in[8];
  const float* gam = (const float*)d_in[9];
  float* out = (float*)d_out;
  char* ws = (char*)d_ws;

  const size_t OFF_WCAT = 0;                                 // 32KB
  const size_t OFF_WO   = 32768;                             // 16KB
  const size_t OFF_BCAT = 49152;                             // 512B
  const size_t OFF_TH   = 65536;                             // 4MB
  const size_t OFF_YWH  = OFF_TH  + (size_t)NB*NN*32*2;      // 3MB
  const size_t OFF_PHI  = OFF_YWH + (size_t)NB*96*16*256*2;  // 512KB
  const size_t OFF_G    = OFF_PHI + (size_t)NB*NM*32*2;      // 1MB
  const size_t OFF_PACC = OFF_G   + (size_t)NB*64*NM*2;      // 16MB
  const size_t OFF_LSUM = OFF_PACC+ (size_t)2*NB*NN*64*2;    // 512KB

  us*    Wcat    = (us*)(ws + OFF_WCAT);
  us*    wob     = (us*)(ws + OFF_WO);
  float* bcat    = (float*)(ws + OFF_BCAT);
  us*    thetaT  = (us*)(ws + OFF_TH);
  us*    Ywh     = (us*)(ws + OFF_YWH);
  us*    phiT    = (us*)(ws + OFF_PHI);
  us*    g_      = (us*)(ws + OFF_G);
  us*    pacc    = (us*)(ws + OFF_PACC);
  float* lsumA   = (float*)(ws + OFF_LSUM);

  k0_prep<<<97, 256, 0, stream>>>(wf, wg, wh, bfp, bgp, bhp, wo, Wcat, wob, bcat);
  k2_conv<<<1024, 256, 0, stream>>>(x, Wcat, bcat, thetaT, Ywh);
  k3_pool<<<384, 256, 0, stream>>>(Ywh, phiT, g_);
  k4_attn<<<1024, 256, 0, stream>>>(thetaT, phiT, g_, pacc, lsumA);
  k5_out<<<1024, 256, 0, stream>>>(x, pacc, lsumA, wob, bo, gam, out);
}

// Round 9
// 171.688 us; speedup vs baseline: 1.0290x; 1.0290x over previous
//
#include <hip/hip_runtime.h>
#include <hip/hip_bf16.h>

// Problem constants (B,C,T,H,W = 4,128,16,32,32)
#define NB 4
#define NC 128
#define NN 16384   // T*H*W
#define NM 2048    // pooled positions

typedef __attribute__((ext_vector_type(8))) short bf16x8;
typedef __attribute__((ext_vector_type(4))) float f32x4;
typedef __attribute__((ext_vector_type(4))) unsigned short u16x4;
typedef __attribute__((ext_vector_type(2))) unsigned int u32x2;
typedef unsigned short us;

#define MFMA16(a,b,c) __builtin_amdgcn_mfma_f32_16x16x32_bf16((a),(b),(c),0,0,0)

__device__ __forceinline__ us f2bf(float f){
  unsigned int u = __float_as_uint(f);
  u += 0x7fffu + ((u >> 16) & 1u);          // RNE
  return (us)(u >> 16);
}
__device__ __forceinline__ float bf2f(us h){
  return __uint_as_float(((unsigned int)h) << 16);
}
// pack two positive floats as bf16 pair (truncation; lo in low half) — proven
__device__ __forceinline__ unsigned int packbf2(float lo, float hi){
  return (__float_as_uint(hi) & 0xffff0000u) | (__float_as_uint(lo) >> 16);
}

// ---------------- K0: weight prep (fp32 -> bf16, concat) — proven ----------------
__global__ void k0_prep(const float* __restrict__ wf, const float* __restrict__ wg,
                        const float* __restrict__ wh, const float* __restrict__ bfp,
                        const float* __restrict__ bgp, const float* __restrict__ bhp,
                        const float* __restrict__ wo,
                        us* __restrict__ Wcat, us* __restrict__ wob,
                        float* __restrict__ bcat){
  int i = blockIdx.x * 256 + threadIdx.x;
  if (i < 16384){
    int o = i >> 7, c = i & 127;
    float v = (o < 32) ? wf[o*128 + c] : (o < 64) ? wg[(o-32)*128 + c] : wh[(o-64)*128 + c];
    Wcat[i] = f2bf(v);
  } else if (i < 24576){
    wob[i - 16384] = f2bf(wo[i - 16384]);
  } else if (i < 24704){
    int k = i - 24576;
    bcat[k] = (k < 32) ? bfp[k] : (k < 64) ? bgp[k-32] : bhp[k-64];
  }
}

// ---------------- K2: fused transpose + 3-conv + relu + w/h-pool — proven (r8) ----------------
__global__ __launch_bounds__(256, 4) void k2_conv(
    const float* __restrict__ x, const us* __restrict__ Wcat,
    const float* __restrict__ bcat,
    us* __restrict__ thetaT, us* __restrict__ Ywh){
  __shared__ __align__(16) us xtile[64*136];     // [n][c] pitch 136
  __shared__ __align__(16) us theta_sh[64*40];   // [n][c0..31] pitch 40
  __shared__ us Ytmp[96*33];                     // w-pooled rows 32..127
  int blk = blockIdx.x;                  // NB * NN/64 = 1024
  int b = blk >> 8, nblk = blk & 255;
  int n0 = nblk * 64;
  int tid = threadIdx.x;

  // stage x[b][c][n0..n0+63] fp32 -> xtile[n][c] bf16 via b128 writes
  {
    int nbase = (tid & 15) * 4;          // 4 n
    int c0 = (tid >> 4) * 8;             // 8 c
    float va[8][4];
    #pragma unroll
    for (int j = 0; j < 8; ++j){
      float4 v = *(const float4*)(x + ((size_t)(b*128 + c0 + j)) * NN + n0 + nbase);
      va[j][0]=v.x; va[j][1]=v.y; va[j][2]=v.z; va[j][3]=v.w;
    }
    #pragma unroll
    for (int nn = 0; nn < 4; ++nn){
      bf16x8 r;
      #pragma unroll
      for (int j = 0; j < 8; ++j) r[j] = (short)f2bf(va[j][nn]);
      *(bf16x8*)&xtile[(nbase+nn)*136 + c0] = r;
    }
  }
  __syncthreads();

  int lane = tid & 63, w = tid >> 6;
  int ln = lane & 15, gq = lane >> 4;
  bf16x8 xf[4];
  #pragma unroll
  for (int kf = 0; kf < 4; ++kf)
    xf[kf] = *(const bf16x8*)&xtile[(w*16+ln)*136 + kf*32 + gq*8];

  #pragma unroll
  for (int ot = 0; ot < 8; ++ot){
    f32x4 acc = {0.f,0.f,0.f,0.f};
    #pragma unroll
    for (int kf = 0; kf < 4; ++kf){
      bf16x8 wfr = *(const bf16x8*)(Wcat + (ot*16 + ln)*128 + kf*32 + gq*8);
      acc = MFMA16(wfr, xf[kf], acc);
    }
    float y[4];
    #pragma unroll
    for (int i = 0; i < 4; ++i){
      int o = ot*16 + gq*4 + i;
      float v = acc[i] + bcat[o];
      y[i] = v > 0.f ? v : 0.f;
    }
    if (ot < 2){
      u16x4 pk;
      #pragma unroll
      for (int i = 0; i < 4; ++i) pk[i] = f2bf(y[i]);
      *(u16x4*)&theta_sh[(w*16+ln)*40 + ot*16 + gq*4] = pk;
    } else {
      #pragma unroll
      for (int i = 0; i < 4; ++i){
        float ym = fmaxf(y[i], __shfl_xor(y[i], 1));
        if ((ln & 1) == 0){
          int r = ot*16 + gq*4 + i - 32;
          Ytmp[r*33 + ((w*16 + ln) >> 1)] = f2bf(ym);
        }
      }
    }
  }
  __syncthreads();

  // theta flush: coalesced 4KB per block
  {
    int row = tid >> 2, coff = (tid & 3) * 8;
    bf16x8 tv = *(const bf16x8*)&theta_sh[row*40 + coff];
    *(bf16x8*)(thetaT + ((size_t)b*NN + n0 + row)*32 + coff) = tv;
  }
  // h-pool: Ytmp[r][j] vs Ytmp[r][j+16] -> Ywh[b][r][t][h2*16 + j]
  int tt = n0 >> 10;          // t index
  int h2 = nblk & 15;         // h-pair index
  #pragma unroll
  for (int q = 0; q < 6; ++q){
    int idx = q*256 + tid;    // 96 r x 16 j
    int r = idx >> 4, j = idx & 15;
    us a = Ytmp[r*33 + j], bsh = Ytmp[r*33 + j + 16];
    us v = a > bsh ? a : bsh;   // bf16 >=0: unsigned compare == fmax
    Ywh[(((size_t)(b*96 + r))*16 + tt)*256 + h2*16 + j] = v;
  }
}

// ---------------- K3: t-pool -> phiT[b][m][32], g[b][c2][m] — proven (r8) ----------------
__global__ void k3_pool(const us* __restrict__ Ywh,
                        us* __restrict__ phiT, us* __restrict__ g_){
  __shared__ us trans[64][36];
  int blk = blockIdx.x;
  int t = threadIdx.x;
  if (blk < 128){
    int b = blk >> 5, mseg = blk & 31;
    int m0 = mseg * 64;
    int u = m0 >> 8, p0 = m0 & 255;
    int c = t >> 3, mj = t & 7;
    const us* r0 = Ywh + (((size_t)(b*96 + c))*16 + 2*u)*256 + p0 + mj*8;
    const us* r1 = r0 + 256;
    #pragma unroll
    for (int k = 0; k < 8; ++k){
      us a = r0[k], bsh = r1[k];
      trans[mj*8 + k][c] = a > bsh ? a : bsh;
    }
    __syncthreads();
    int ml = t >> 2, cg = t & 3;
    u16x4 o0, o1;
    #pragma unroll
    for (int k = 0; k < 4; ++k){ o0[k] = trans[ml][cg*8 + k]; o1[k] = trans[ml][cg*8 + 4 + k]; }
    *(u16x4*)(phiT + ((size_t)b*NM + m0 + ml)*32 + cg*8)     = o0;
    *(u16x4*)(phiT + ((size_t)b*NM + m0 + ml)*32 + cg*8 + 4) = o1;
  } else {
    int blk2 = blk - 128;
    int b = blk2 >> 6, c2 = blk2 & 63;
    int u = t >> 5, p = (t & 31) * 8;
    const us* r0 = Ywh + (((size_t)(b*96 + 32 + c2))*16 + 2*u)*256 + p;
    const us* r1 = r0 + 256;
    u16x4 o0, o1;
    #pragma unroll
    for (int k = 0; k < 4; ++k){
      us a0 = r0[k],   b0 = r1[k];
      us a1 = r0[4+k], b1 = r1[4+k];
      o0[k] = a0 > b0 ? a0 : b0;
      o1[k] = a1 > b1 ? a1 : b1;
    }
    *(u16x4*)(g_ + ((size_t)(b*64 + c2))*NM + t*8)     = o0;
    *(u16x4*)(g_ + ((size_t)(b*64 + c2))*NM + t*8 + 4) = o1;
  }
}

// ---------------- K4: flash attention + wo-conv + residual (fused k4+k5) ----------------
// Main loop = round-2-proven k4 (pitch-40 LDS, __expf, packbf2), full 2048 keys (64 chunks).
// Epilogue = k5's proven wo-MFMA fragment/store layout, ag via per-wave LDS tile.
__global__ __launch_bounds__(256, 2) void k4_attn_out(
    const us* __restrict__ thetaT, const us* __restrict__ phiT,
    const us* __restrict__ g_, const us* __restrict__ wob,
    const float* __restrict__ bo, const float* __restrict__ gamma,
    const float* __restrict__ x, float* __restrict__ out){
  __shared__ __align__(16) us smem[10240];   // 20480 B
  // main-loop layout (us offsets): phi [2][32][40] @0 ; g [2][64][40] @2560 ; P [4][16][40] @7680
  us* phi_lds = smem;
  us* g_lds   = smem + 2560;
  us* P_lds   = smem + 7680;

  int bx = blockIdx.x;                               // 512
  int b = bx >> 7, qb = bx & 127;
  int tid = threadIdx.x;
  int lane = tid & 63, wv = tid >> 6;
  int ln = lane & 15, gq = lane >> 4;
  int nq = qb*128 + wv*32;

  const us* thb = thetaT + (size_t)b*NN*32;
  const us* phb = phiT   + (size_t)b*NM*32;
  const us* gb  = g_     + (size_t)b*64*NM;

  bf16x8 thf0 = *(const bf16x8*)(thb + (size_t)(nq + ln)*32 + gq*8);
  bf16x8 thf1 = *(const bf16x8*)(thb + (size_t)(nq + 16 + ln)*32 + gq*8);

  f32x4 acc[2][4];
  #pragma unroll
  for (int q = 0; q < 2; ++q)
    #pragma unroll
    for (int c2t = 0; c2t < 4; ++c2t) acc[q][c2t] = (f32x4){0.f,0.f,0.f,0.f};
  float lsum0 = 0.f, lsum1 = 0.f;

  // staging: g by all 256 threads; phi by tid<128 (round-2-proven mapping, ch0=0)
  int gr = tid >> 2, gp = tid & 3;
  const us* sgp_g = gb + (size_t)gr*NM + gp*8;
  us* slg0 = &g_lds[0*2560 + gr*40 + gp*8];
  us* slg1 = &g_lds[1*2560 + gr*40 + gp*8];
  bool hasphi = tid < 128;
  int pr = (tid >> 2) & 31, pp = tid & 3;
  const us* sgp_p = phb + (size_t)pr*32 + pp*8;
  us* slp0 = &phi_lds[0*1280 + pr*40 + pp*8];
  us* slp1 = &phi_lds[1*1280 + pr*40 + pp*8];

  { bf16x8 srg = *(const bf16x8*)(sgp_g); *(bf16x8*)slg0 = srg; }
  if (hasphi){ bf16x8 srp = *(const bf16x8*)(sgp_p); *(bf16x8*)slp0 = srp; }
  __syncthreads();

  bf16x8 srg_n = {}, srp_n = {};
  for (int lc = 0; lc < 64; ++lc){
    int cur = lc & 1;
    if (lc + 1 < 64){                             // issue-early (T14)
      srg_n = *(const bf16x8*)(sgp_g + (size_t)(lc+1)*32);
      if (hasphi) srp_n = *(const bf16x8*)(sgp_p + (size_t)(lc+1)*1024);
    }
    bf16x8 pf0 = *(const bf16x8*)(&phi_lds[cur*1280 + ln*40 + gq*8]);
    bf16x8 pf1 = *(const bf16x8*)(&phi_lds[cur*1280 + (16+ln)*40 + gq*8]);
    bf16x8 gf0 = *(const bf16x8*)(&g_lds[cur*2560 + ln*40 + gq*8]);
    bf16x8 gf1 = *(const bf16x8*)(&g_lds[cur*2560 + (16+ln)*40 + gq*8]);
    bf16x8 gf2 = *(const bf16x8*)(&g_lds[cur*2560 + (32+ln)*40 + gq*8]);
    bf16x8 gf3 = *(const bf16x8*)(&g_lds[cur*2560 + (48+ln)*40 + gq*8]);
    f32x4 z = {0.f,0.f,0.f,0.f};

    // ---- q tile 0 ----
    {
      f32x4 s0 = MFMA16(pf0, thf0, z);
      f32x4 s1 = MFMA16(pf1, thf0, z);
      float p0[4], p1[4];
      #pragma unroll
      for (int i = 0; i < 4; ++i){ p0[i] = __expf(s0[i]); p1[i] = __expf(s1[i]); }
      lsum0 += ((p0[0]+p0[1]) + (p0[2]+p0[3])) + ((p1[0]+p1[1]) + (p1[2]+p1[3]));
      u32x2 w0 = { packbf2(p0[0],p0[1]), packbf2(p0[2],p0[3]) };
      u32x2 w1 = { packbf2(p1[0],p1[1]), packbf2(p1[2],p1[3]) };
      *(u32x2*)(&P_lds[wv*640 + ln*40 + gq*4])      = w0;
      *(u32x2*)(&P_lds[wv*640 + ln*40 + 16 + gq*4]) = w1;
      bf16x8 paf = *(const bf16x8*)(&P_lds[wv*640 + ln*40 + gq*8]);
      acc[0][0] = MFMA16(paf, gf0, acc[0][0]);
      acc[0][1] = MFMA16(paf, gf1, acc[0][1]);
      acc[0][2] = MFMA16(paf, gf2, acc[0][2]);
      acc[0][3] = MFMA16(paf, gf3, acc[0][3]);
    }
    // ---- q tile 1 ----
    {
      f32x4 s0 = MFMA16(pf0, thf1, z);
      f32x4 s1 = MFMA16(pf1, thf1, z);
      float p0[4], p1[4];
      #pragma unroll
      for (int i = 0; i < 4; ++i){ p0[i] = __expf(s0[i]); p1[i] = __expf(s1[i]); }
      lsum1 += ((p0[0]+p0[1]) + (p0[2]+p0[3])) + ((p1[0]+p1[1]) + (p1[2]+p1[3]));
      u32x2 w0 = { packbf2(p0[0],p0[1]), packbf2(p0[2],p0[3]) };
      u32x2 w1 = { packbf2(p1[0],p1[1]), packbf2(p1[2],p1[3]) };
      *(u32x2*)(&P_lds[wv*640 + ln*40 + gq*4])      = w0;
      *(u32x2*)(&P_lds[wv*640 + ln*40 + 16 + gq*4]) = w1;
      bf16x8 paf = *(const bf16x8*)(&P_lds[wv*640 + ln*40 + gq*8]);
      acc[1][0] = MFMA16(paf, gf0, acc[1][0]);
      acc[1][1] = MFMA16(paf, gf1, acc[1][1]);
      acc[1][2] = MFMA16(paf, gf2, acc[1][2]);
      acc[1][3] = MFMA16(paf, gf3, acc[1][3]);
    }
    if (lc + 1 < 64){                             // write-late into other buffer
      *(bf16x8*)(((lc+1)&1) ? slg1 : slg0) = srg_n;
      if (hasphi) *(bf16x8*)(((lc+1)&1) ? slp1 : slp0) = srp_n;
    }
    __syncthreads();
  }
  // all waves synced past last LDS use of phi/g/P -> safe to reuse smem for ag tiles

  lsum0 += __shfl_xor(lsum0, 16); lsum0 += __shfl_xor(lsum0, 32);
  lsum1 += __shfl_xor(lsum1, 16); lsum1 += __shfl_xor(lsum1, 32);

  // normalize in-register, write per-wave ag tile [32 n][72 pitch] us (16B-aligned rows)
  us* ag = smem + wv*2304;                 // 32*72 = 2304 us per wave; 4*2304=9216 <= 10240
  float inv0[4], inv1[4];
  #pragma unroll
  for (int i = 0; i < 4; ++i){
    inv0[i] = 1.0f / __shfl(lsum0, gq*4 + i);
    inv1[i] = 1.0f / __shfl(lsum1, gq*4 + i);
  }
  #pragma unroll
  for (int c2t = 0; c2t < 4; ++c2t)
    #pragma unroll
    for (int i = 0; i < 4; ++i){
      ag[(gq*4 + i)*72      + c2t*16 + ln] = f2bf(acc[0][c2t][i] * inv0[i]);
      ag[(16 + gq*4 + i)*72 + c2t*16 + ln] = f2bf(acc[1][c2t][i] * inv1[i]);
    }
  // same-wave LDS RAW: compiler inserts lgkmcnt; no barrier needed (wave-private tile)

  float gam = gamma[0];
  #pragma unroll
  for (int qt = 0; qt < 2; ++qt){
    bf16x8 bfr0 = *(const bf16x8*)(&ag[(qt*16 + ln)*72 + gq*8]);
    bf16x8 bfr1 = *(const bf16x8*)(&ag[(qt*16 + ln)*72 + 32 + gq*8]);
    int n = nq + qt*16 + ln;
    #pragma unroll
    for (int ot = 0; ot < 8; ++ot){
      f32x4 a2 = {0.f,0.f,0.f,0.f};
      bf16x8 a0 = *(const bf16x8*)(wob + (ot*16 + ln)*64 + gq*8);
      bf16x8 a1 = *(const bf16x8*)(wob + (ot*16 + ln)*64 + 32 + gq*8);
      a2 = MFMA16(a0, bfr0, a2);
      a2 = MFMA16(a1, bfr1, a2);
      #pragma unroll
      for (int i = 0; i < 4; ++i){
        int o = ot*16 + gq*4 + i;
        size_t idx = ((size_t)b*128 + o)*NN + n;
        float v = a2[i] + bo[o];
        v = v > 0.f ? v : 0.f;
        out[idx] = x[idx] + gam * v;
      }
    }
  }
}

extern "C" void kernel_launch(void* const* d_in, const int* in_sizes, int n_in,
                              void* d_out, int out_size, void* d_ws, size_t ws_size,
                              hipStream_t stream){
  const float* x   = (const float*)d_in[0];
  const float* wf  = (const float*)d_in[1];
  const float* bfp = (const float*)d_in[2];
  const float* wg  = (const float*)d_in[3];
  const float* bgp = (const float*)d_in[4];
  const float* wh  = (const float*)d_in[5];
  const float* bhp = (const float*)d_in[6];
  const float* wo  = (const float*)d_in[7];
  const float* bo  = (const float*)d_in[8];
  const float* gam = (const float*)d_in[9];
  float* out = (float*)d_out;
  char* ws = (char*)d_ws;

  const size_t OFF_WCAT = 0;                                 // 32KB
  const size_t OFF_WO   = 32768;                             // 16KB
  const size_t OFF_BCAT = 49152;                             // 512B
  const size_t OFF_TH   = 65536;                             // 4MB
  const size_t OFF_YWH  = OFF_TH  + (size_t)NB*NN*32*2;      // 3MB
  const size_t OFF_PHI  = OFF_YWH + (size_t)NB*96*16*256*2;  // 512KB
  const size_t OFF_G    = OFF_PHI + (size_t)NB*NM*32*2;      // 1MB

  us*    Wcat    = (us*)(ws + OFF_WCAT);
  us*    wob     = (us*)(ws + OFF_WO);
  float* bcat    = (float*)(ws + OFF_BCAT);
  us*    thetaT  = (us*)(ws + OFF_TH);
  us*    Ywh     = (us*)(ws + OFF_YWH);
  us*    phiT    = (us*)(ws + OFF_PHI);
  us*    g_      = (us*)(ws + OFF_G);

  k0_prep<<<97, 256, 0, stream>>>(wf, wg, wh, bfp, bgp, bhp, wo, Wcat, wob, bcat);
  k2_conv<<<1024, 256, 0, stream>>>(x, Wcat, bcat, thetaT, Ywh);
  k3_pool<<<384, 256, 0, stream>>>(Ywh, phiT, g_);
  k4_attn_out<<<512, 256, 0, stream>>>(thetaT, phiT, g_, wob, bo, gam, x, out);
}